// Round 5
// baseline (191.487 us; speedup 1.0000x reference)
//
#include <hip/hip_runtime.h>
#include <stdint.h>

// Problem constants (from reference)
#define NNODES 50000
#define NEDGES 1000000
#define DIM    64
#define NREL   8
#define MT     3125         // NNODES / 16
#define NBUCK  196          // ceil(50000/256); bucket = dst >> 8 (256-node range)
#define BCAP   5632         // per-bucket staging capacity (expected ~5102, +7.4 sigma)
#define KEYS   2048         // 256 nodes x 8 rels per bucket

typedef __attribute__((ext_vector_type(8))) short short8;
typedef __attribute__((ext_vector_type(4))) float float4v;
typedef __attribute__((ext_vector_type(4))) unsigned short us4;

__device__ __forceinline__ float bf2f(unsigned short u) {
  return __uint_as_float(((unsigned int)u) << 16);
}
__device__ __forceinline__ unsigned short f2bf(float f) {
  unsigned int u = __float_as_uint(f);
  unsigned int r = (u + 0x7FFF + ((u >> 16) & 1)) >> 16;   // round-nearest-even
  return (unsigned short)r;
}

// K0: build MFMA B fragments for Bmat[576][64] = [W_linear ; W_self] (bf16) + fused bias.
// Bf2[((ks*4+ct)*64 + l)*8 + j] = Bmat[ks*32 + (l>>4)*8 + j][ct*16 + (l&15)]
__global__ void prep_kernel(const float* __restrict__ Wlin,
                            const float* __restrict__ Wself,
                            const float* __restrict__ blin,
                            const float* __restrict__ bself,
                            unsigned short* __restrict__ Bf2,
                            float* __restrict__ bsum) {
  int t = blockIdx.x * blockDim.x + threadIdx.x;
  if (t < 18 * 4 * 64 * 8) {
    int j  = t & 7;
    int l  = (t >> 3) & 63;
    int ct = (t >> 9) & 3;
    int ks = t >> 11;
    int k = ks * 32 + (l >> 4) * 8 + j;
    int c = ct * 16 + (l & 15);
    float v = (k < 512) ? Wlin[(size_t)k * 64 + c] : Wself[(size_t)(k - 512) * 64 + c];
    Bf2[t] = f2bf(v);
  }
  if (t < 64) bsum[t] = blin[t] + bself[t];
}

// K0b: cast x f32 -> bf16 (6.4 MB hot gather source)
__global__ void cast_kernel(const float4* __restrict__ x4, us4* __restrict__ xb, int n4) {
  int t = blockIdx.x * 256 + threadIdx.x;
  if (t >= n4) return;
  float4 v = x4[t];
  us4 o;
  o.x = f2bf(v.x); o.y = f2bf(v.y); o.z = f2bf(v.z); o.w = f2bf(v.w);
  xb[t] = o;
}

// K1: two-level binned scatter. Record: x = src(16) | rel(3)<<16 | dst_low(8)<<19, y = w bits.
__global__ __launch_bounds__(1024) void binscatter_kernel(
    const int4* __restrict__ src4, const int4* __restrict__ dst4,
    const int4* __restrict__ rel4, const float4* __restrict__ w4,
    int* __restrict__ bucket_cursor, uint2* __restrict__ staged, int E4) {
  __shared__ int lhist[NBUCK];
  __shared__ int lbase[NBUCK];
  int tid = threadIdx.x;
  if (tid < NBUCK) lhist[tid] = 0;
  __syncthreads();
  int t = blockIdx.x * 1024 + tid;
  bool valid = t < E4;
  int4 s = {0,0,0,0}, d = {0,0,0,0}, r = {0,0,0,0};
  float4 w = {0.f,0.f,0.f,0.f};
  if (valid) { s = src4[t]; d = dst4[t]; r = rel4[t]; w = w4[t]; }
  int b0=0,b1=0,b2=0,b3=0,p0=0,p1=0,p2=0,p3=0;
  if (valid) {
    b0 = d.x >> 8; p0 = atomicAdd(&lhist[b0], 1);
    b1 = d.y >> 8; p1 = atomicAdd(&lhist[b1], 1);
    b2 = d.z >> 8; p2 = atomicAdd(&lhist[b2], 1);
    b3 = d.w >> 8; p3 = atomicAdd(&lhist[b3], 1);
  }
  __syncthreads();
  if (tid < NBUCK && lhist[tid] > 0)
    lbase[tid] = atomicAdd(&bucket_cursor[tid], lhist[tid]);
  __syncthreads();
  if (valid) {
    int i0 = lbase[b0] + p0, i1 = lbase[b1] + p1, i2 = lbase[b2] + p2, i3 = lbase[b3] + p3;
    if (i0 < BCAP) staged[(size_t)b0 * BCAP + i0] =
      make_uint2((unsigned)s.x | ((unsigned)r.x << 16) | ((unsigned)(d.x & 255) << 19), __float_as_uint(w.x));
    if (i1 < BCAP) staged[(size_t)b1 * BCAP + i1] =
      make_uint2((unsigned)s.y | ((unsigned)r.y << 16) | ((unsigned)(d.y & 255) << 19), __float_as_uint(w.y));
    if (i2 < BCAP) staged[(size_t)b2 * BCAP + i2] =
      make_uint2((unsigned)s.z | ((unsigned)r.z << 16) | ((unsigned)(d.z & 255) << 19), __float_as_uint(w.z));
    if (i3 < BCAP) staged[(size_t)b3 * BCAP + i3] =
      make_uint2((unsigned)s.w | ((unsigned)r.w << 16) | ((unsigned)(d.w & 255) << 19), __float_as_uint(w.w));
  }
}

// K2: single-wave exclusive scan of 196 bucket counts -> CSR bucket bases
__global__ void bucketscan_kernel(const int* __restrict__ counts, int* __restrict__ bbase) {
  int lane = threadIdx.x;  // 64 threads
  int carry = 0;
  for (int s = 0; s < NBUCK; s += 64) {
    int i = s + lane;
    int v = (i < NBUCK) ? counts[i] : 0;
    int inc = v;
    #pragma unroll
    for (int d = 1; d < 64; d <<= 1) {
      int tt = __shfl_up(inc, d);
      if (lane >= d) inc += tt;
    }
    if (i < NBUCK) bbase[i] = carry + inc - v;
    carry += __shfl(inc, 63);
  }
  if (lane == 0) bbase[NBUCK] = carry;
}

// K3: per-bucket CSR build keyed by (dst_low, rel): 2048-key LDS hist + scan ->
// roff[node*8+r] segment offsets; meta = (src, w/deg) with normalization pre-applied.
__global__ __launch_bounds__(1024) void csrbuild_kernel(
    const int* __restrict__ bucket_cursor, const int* __restrict__ bbase,
    const uint2* __restrict__ staged, uint2* __restrict__ meta, int* __restrict__ roff) {
  __shared__ int   nhist[KEYS];
  __shared__ int   ncur[KEYS];
  __shared__ float degf[KEYS];
  int b = blockIdx.x;
  int tid = threadIdx.x;
  int cnt  = bucket_cursor[b];
  if (cnt > BCAP) cnt = BCAP;
  int base = bbase[b];
  for (int i = tid; i < KEYS; i += 1024) { nhist[i] = 0; degf[i] = 0.f; }
  __syncthreads();
  const uint2* sb = staged + (size_t)b * BCAP;
  for (int i = tid; i < cnt; i += 1024) {
    uint2 rec = sb[i];
    int key = (((rec.x >> 19) & 255) << 3) | ((rec.x >> 16) & 7);
    atomicAdd(&nhist[key], 1);
    atomicAdd(&degf[key], __uint_as_float(rec.y));
  }
  __syncthreads();
  if (tid < 64) {    // wave 0: scan 2048 (32 chunks of 64, serial carry)
    int carry = 0;
    #pragma unroll
    for (int s = 0; s < KEYS / 64; s++) {
      int v = nhist[s * 64 + tid];
      int inc = v;
      #pragma unroll
      for (int d = 1; d < 64; d <<= 1) {
        int tt = __shfl_up(inc, d);
        if (tid >= d) inc += tt;
      }
      ncur[s * 64 + tid] = carry + inc - v;
      carry += __shfl(inc, 63);
    }
  }
  __syncthreads();
  // write roff + invert degrees
  int gk0 = b * KEYS;
  int nk = NNODES * NREL - gk0; if (nk > KEYS) nk = KEYS;
  for (int i = tid; i < nk; i += 1024) roff[gk0 + i] = base + ncur[i];
  if (b == 0 && tid == 0) roff[NNODES * NREL] = NEDGES;
  for (int i = tid; i < KEYS; i += 1024) {
    float d = degf[i];
    degf[i] = (d != 0.f) ? (1.0f / d) : 0.f;
  }
  __syncthreads();
  for (int i = tid; i < cnt; i += 1024) {
    uint2 rec = sb[i];
    int key = (((rec.x >> 19) & 255) << 3) | ((rec.x >> 16) & 7);
    int pos = atomicAdd(&ncur[key], 1);
    float sc = __uint_as_float(rec.y) * degf[key];
    meta[base + pos] = make_uint2(rec.x & 0xFFFF, __float_as_uint(sc));
  }
}

// K4: x-space aggregation. One wave per dst node; edges rel-sorted; gather source
// is the 6.4 MB bf16 x (L2-resident). update[node][r*64+lane] = sum scale*x[src][lane].
__global__ __launch_bounds__(256) void aggregate_kernel(const int* __restrict__ roff,
                                                        const uint2* __restrict__ meta,
                                                        const unsigned short* __restrict__ xb,
                                                        unsigned short* __restrict__ update) {
  int node = blockIdx.x * 4 + (threadIdx.x >> 6);
  int lane = threadIdx.x & 63;
  int bnd = 0;
  if (lane < 9) bnd = roff[node * NREL + lane];
  int b0 = __shfl(bnd, 0);
  int cnt = __shfl(bnd, 8) - b0;
  int cl = (cnt < 64) ? cnt : 64;

  uint2 mm = make_uint2(0u, 0u);
  if (lane < cl) mm = meta[b0 + lane];           // coalesced 8B/lane
  int   off_l = (mm.x & 0xFFFF) * 64;
  float sc_l  = __uint_as_float(mm.y);

  float acc[8];
  #pragma unroll
  for (int r = 0; r < 8; r++) acc[r] = 0.f;

  #pragma unroll
  for (int r = 0; r < 8; r++) {
    int e0 = __shfl(bnd, r) - b0;
    int e1 = __shfl(bnd, r + 1) - b0;
    int jend = (e1 < 64) ? e1 : 64;
    int j = (e0 < jend) ? e0 : jend;
    for (; j + 2 <= jend; j += 2) {
      int   o0 = __shfl(off_l, j), o1 = __shfl(off_l, j + 1);
      float s0 = __shfl(sc_l, j),  s1 = __shfl(sc_l, j + 1);
      float v0 = bf2f(xb[o0 + lane]);
      float v1 = bf2f(xb[o1 + lane]);
      acc[r] += s0 * v0;
      acc[r] += s1 * v1;
    }
    for (; j < jend; j++) {
      int   o = __shfl(off_l, j);
      float s = __shfl(sc_l, j);
      acc[r] += s * bf2f(xb[o + lane]);
    }
    // rare tail (node degree > 64)
    int estart = (e0 > 64) ? e0 : 64;
    for (int e = estart; e < e1; e++) {
      uint2 m = meta[b0 + e];
      acc[r] += __uint_as_float(m.y) * bf2f(xb[(m.x & 0xFFFF) * 64 + lane]);
    }
  }
  unsigned short* up = update + (size_t)node * 512 + lane;
  #pragma unroll
  for (int r = 0; r < 8; r++) up[r * 64] = f2bf(acc[r]);
}

// K5: out[N][64] = [update | xb] [N][576] @ Bmat[576][64] + bias, relu.
// One wave per 16-row tile; 18 k-steps x 4 col-tiles; fp32 MFMA accumulate.
__global__ __launch_bounds__(256) void gemm2_kernel(const unsigned short* __restrict__ update,
                                                    const unsigned short* __restrict__ xb,
                                                    const unsigned short* __restrict__ Bf2,
                                                    const float* __restrict__ bsum,
                                                    float* __restrict__ out) {
  int mt = blockIdx.x * 4 + (threadIdx.x >> 6);
  if (mt >= MT) return;
  int lane = threadIdx.x & 63;
  int m0 = mt * 16 + (lane & 15);
  int q  = lane >> 4;
  const unsigned short* arow = update + (size_t)m0 * 512 + q * 8;
  const unsigned short* xrow = xb + (size_t)m0 * 64 + q * 8;
  float4v a0 = {0.f,0.f,0.f,0.f}, a1 = a0, a2 = a0, a3 = a0;
  #pragma unroll
  for (int ks = 0; ks < 18; ks++) {
    short8 a;
    if (ks < 16) a = *(const short8*)(arow + ks * 32);
    else         a = *(const short8*)(xrow + (ks - 16) * 32);
    const short8* bp = (const short8*)Bf2 + (size_t)(ks * 4) * 64 + lane;
    a0 = __builtin_amdgcn_mfma_f32_16x16x32_bf16(a, bp[0],   a0, 0, 0, 0);
    a1 = __builtin_amdgcn_mfma_f32_16x16x32_bf16(a, bp[64],  a1, 0, 0, 0);
    a2 = __builtin_amdgcn_mfma_f32_16x16x32_bf16(a, bp[128], a2, 0, 0, 0);
    a3 = __builtin_amdgcn_mfma_f32_16x16x32_bf16(a, bp[192], a3, 0, 0, 0);
  }
  int rowb = mt * 16 + q * 4;
  int c0 = lane & 15;
  float4v accs[4] = {a0, a1, a2, a3};
  #pragma unroll
  for (int ct = 0; ct < 4; ct++) {
    int col = ct * 16 + c0;
    float bias = bsum[col];
    #pragma unroll
    for (int rr = 0; rr < 4; rr++) {
      out[(size_t)(rowb + rr) * 64 + col] = fmaxf(accs[ct][rr] + bias, 0.0f);
    }
  }
}

extern "C" void kernel_launch(void* const* d_in, const int* in_sizes, int n_in,
                              void* d_out, int out_size, void* d_ws, size_t ws_size,
                              hipStream_t stream) {
  const float* x     = (const float*)d_in[0];
  const int*   esrc  = (const int*)d_in[1];
  const int*   edst  = (const int*)d_in[2];
  const int*   erel  = (const int*)d_in[3];
  const float* ew    = (const float*)d_in[4];
  const float* Wlin  = (const float*)d_in[5];
  const float* blin  = (const float*)d_in[6];
  const float* Wself = (const float*)d_in[7];
  const float* bself = (const float*)d_in[8];
  float* out = (float*)d_out;

  char* ws = (char*)d_ws;
  size_t off = 0;
  auto alloc = [&](size_t bytes) -> void* {
    void* p = ws + off;
    off += (bytes + 255) & ~(size_t)255;
    return p;
  };
  int*            bucket_cursor = (int*)alloc((size_t)NBUCK * sizeof(int));            // zeroed
  int*            bbase   = (int*)alloc((size_t)(NBUCK + 1) * sizeof(int));
  int*            roff    = (int*)alloc((size_t)(NNODES * NREL + 8) * sizeof(int));    // 1.6 MB
  uint2*          staged  = (uint2*)alloc((size_t)NBUCK * BCAP * sizeof(uint2));       // 8.8 MB
  uint2*          meta    = (uint2*)alloc((size_t)NEDGES * sizeof(uint2));             // 8 MB
  unsigned short* Bf2     = (unsigned short*)alloc((size_t)18 * 4 * 64 * 8 * sizeof(unsigned short));
  float*          bsum    = (float*)alloc(64 * sizeof(float));
  unsigned short* xb      = (unsigned short*)alloc((size_t)NNODES * DIM * sizeof(unsigned short));   // 6.4 MB
  unsigned short* update  = (unsigned short*)alloc((size_t)NNODES * 512 * sizeof(unsigned short));   // 51.2 MB

  hipMemsetAsync(bucket_cursor, 0, (size_t)NBUCK * sizeof(int), stream);

  const int E4 = NEDGES / 4;
  const int X4 = NNODES * DIM / 4;
  prep_kernel<<<(18 * 4 * 64 * 8 + 255) / 256, 256, 0, stream>>>(Wlin, Wself, blin, bself, Bf2, bsum);
  cast_kernel<<<(X4 + 255) / 256, 256, 0, stream>>>((const float4*)x, (us4*)xb, X4);
  binscatter_kernel<<<(E4 + 1023) / 1024, 1024, 0, stream>>>((const int4*)esrc, (const int4*)edst,
                                                             (const int4*)erel, (const float4*)ew,
                                                             bucket_cursor, staged, E4);
  bucketscan_kernel<<<1, 64, 0, stream>>>(bucket_cursor, bbase);
  csrbuild_kernel<<<NBUCK, 1024, 0, stream>>>(bucket_cursor, bbase, staged, meta, roff);
  aggregate_kernel<<<NNODES / 4, 256, 0, stream>>>(roff, meta, xb, update);
  gemm2_kernel<<<(MT + 3) / 4, 256, 0, stream>>>(update, xb, Bf2, bsum, out);
}

// Round 6
// 176.955 us; speedup vs baseline: 1.0821x; 1.0821x over previous
//
#include <hip/hip_runtime.h>
#include <stdint.h>

// Problem constants (from reference)
#define NNODES 50000
#define NEDGES 1000000
#define DIM    64
#define NREL   8
#define NBUCK  196          // ceil(50000/256); bucket = dst >> 8 (256-node range)
#define BCAP   5632         // per-bucket staging capacity (expected ~5102, +7.4 sigma)
#define KEYS   2048         // 256 nodes x 8 rels per bucket
#define APITCH 584          // LDS A-tile pitch (576 + 8): breaks pow2 bank stride, keeps 16B align

typedef __attribute__((ext_vector_type(8))) short short8;
typedef __attribute__((ext_vector_type(4))) float float4v;
typedef __attribute__((ext_vector_type(4))) unsigned short us4;

__device__ __forceinline__ float bf2f(unsigned short u) {
  return __uint_as_float(((unsigned int)u) << 16);
}
__device__ __forceinline__ unsigned short f2bf(float f) {
  unsigned int u = __float_as_uint(f);
  unsigned int r = (u + 0x7FFF + ((u >> 16) & 1)) >> 16;   // round-nearest-even
  return (unsigned short)r;
}

// K0: build MFMA B fragments for Bmat[576][64] = [W_linear ; W_self] (bf16) + fused bias.
// Bf2[((ks*4+ct)*64 + l)*8 + j] = Bmat[ks*32 + (l>>4)*8 + j][ct*16 + (l&15)]
__global__ void prep_kernel(const float* __restrict__ Wlin,
                            const float* __restrict__ Wself,
                            const float* __restrict__ blin,
                            const float* __restrict__ bself,
                            unsigned short* __restrict__ Bf2,
                            float* __restrict__ bsum) {
  int t = blockIdx.x * blockDim.x + threadIdx.x;
  if (t < 18 * 4 * 64 * 8) {
    int j  = t & 7;
    int l  = (t >> 3) & 63;
    int ct = (t >> 9) & 3;
    int ks = t >> 11;
    int k = ks * 32 + (l >> 4) * 8 + j;
    int c = ct * 16 + (l & 15);
    float v = (k < 512) ? Wlin[(size_t)k * 64 + c] : Wself[(size_t)(k - 512) * 64 + c];
    Bf2[t] = f2bf(v);
  }
  if (t < 64) bsum[t] = blin[t] + bself[t];
}

// K0b: cast x f32 -> bf16 (gather source); also zero bucket_cursor (runs before binscatter)
__global__ void cast_kernel(const float4* __restrict__ x4, us4* __restrict__ xb,
                            int* __restrict__ bucket_cursor, int n4) {
  int t = blockIdx.x * 256 + threadIdx.x;
  if (t < NBUCK) bucket_cursor[t] = 0;
  if (t >= n4) return;
  float4 v = x4[t];
  us4 o;
  o.x = f2bf(v.x); o.y = f2bf(v.y); o.z = f2bf(v.z); o.w = f2bf(v.w);
  xb[t] = o;
}

// K1: two-level binned scatter. Record: x = src(16) | rel(3)<<16 | dst_low(8)<<19, y = w bits.
__global__ __launch_bounds__(1024) void binscatter_kernel(
    const int4* __restrict__ src4, const int4* __restrict__ dst4,
    const int4* __restrict__ rel4, const float4* __restrict__ w4,
    int* __restrict__ bucket_cursor, uint2* __restrict__ staged, int E4) {
  __shared__ int lhist[NBUCK];
  __shared__ int lbase[NBUCK];
  int tid = threadIdx.x;
  if (tid < NBUCK) lhist[tid] = 0;
  __syncthreads();
  int t = blockIdx.x * 1024 + tid;
  bool valid = t < E4;
  int4 s = {0,0,0,0}, d = {0,0,0,0}, r = {0,0,0,0};
  float4 w = {0.f,0.f,0.f,0.f};
  if (valid) { s = src4[t]; d = dst4[t]; r = rel4[t]; w = w4[t]; }
  int b0=0,b1=0,b2=0,b3=0,p0=0,p1=0,p2=0,p3=0;
  if (valid) {
    b0 = d.x >> 8; p0 = atomicAdd(&lhist[b0], 1);
    b1 = d.y >> 8; p1 = atomicAdd(&lhist[b1], 1);
    b2 = d.z >> 8; p2 = atomicAdd(&lhist[b2], 1);
    b3 = d.w >> 8; p3 = atomicAdd(&lhist[b3], 1);
  }
  __syncthreads();
  if (tid < NBUCK && lhist[tid] > 0)
    lbase[tid] = atomicAdd(&bucket_cursor[tid], lhist[tid]);
  __syncthreads();
  if (valid) {
    int i0 = lbase[b0] + p0, i1 = lbase[b1] + p1, i2 = lbase[b2] + p2, i3 = lbase[b3] + p3;
    if (i0 < BCAP) staged[(size_t)b0 * BCAP + i0] =
      make_uint2((unsigned)s.x | ((unsigned)r.x << 16) | ((unsigned)(d.x & 255) << 19), __float_as_uint(w.x));
    if (i1 < BCAP) staged[(size_t)b1 * BCAP + i1] =
      make_uint2((unsigned)s.y | ((unsigned)r.y << 16) | ((unsigned)(d.y & 255) << 19), __float_as_uint(w.y));
    if (i2 < BCAP) staged[(size_t)b2 * BCAP + i2] =
      make_uint2((unsigned)s.z | ((unsigned)r.z << 16) | ((unsigned)(d.z & 255) << 19), __float_as_uint(w.z));
    if (i3 < BCAP) staged[(size_t)b3 * BCAP + i3] =
      make_uint2((unsigned)s.w | ((unsigned)r.w << 16) | ((unsigned)(d.w & 255) << 19), __float_as_uint(w.w));
  }
}

// K2: per-bucket CSR build keyed by (dst_low, rel): 2048-key LDS hist + scan ->
// roff[node*8+r]; meta = (src, w/deg) pre-normalized. Bucket base computed inline
// (prefix sum over 196 bucket counts by wave 0 — no separate scan kernel).
__global__ __launch_bounds__(1024) void csrbuild_kernel(
    const int* __restrict__ bucket_cursor,
    const uint2* __restrict__ staged, uint2* __restrict__ meta, int* __restrict__ roff) {
  __shared__ int   nhist[KEYS];
  __shared__ int   ncur[KEYS];
  __shared__ float degf[KEYS];
  __shared__ int   base_s;
  int b = blockIdx.x;
  int tid = threadIdx.x;
  int cnt  = bucket_cursor[b];
  if (cnt > BCAP) cnt = BCAP;
  for (int i = tid; i < KEYS; i += 1024) { nhist[i] = 0; degf[i] = 0.f; }
  if (tid >= 64 && tid < 128) {          // wave 1: bucket base = sum of counts before b
    int l = tid - 64;
    int s = 0;
    for (int i = l; i < b; i += 64) {
      int c = bucket_cursor[i];
      s += (c < BCAP) ? c : BCAP;
    }
    #pragma unroll
    for (int d = 1; d < 64; d <<= 1) s += __shfl_xor(s, d);
    if (l == 0) base_s = s;
  }
  __syncthreads();
  int base = base_s;
  const uint2* sb = staged + (size_t)b * BCAP;
  for (int i = tid; i < cnt; i += 1024) {
    uint2 rec = sb[i];
    int key = (((rec.x >> 19) & 255) << 3) | ((rec.x >> 16) & 7);
    atomicAdd(&nhist[key], 1);
    atomicAdd(&degf[key], __uint_as_float(rec.y));
  }
  __syncthreads();
  if (tid < 64) {    // wave 0: scan 2048 (32 chunks of 64, serial carry)
    int carry = 0;
    #pragma unroll
    for (int s = 0; s < KEYS / 64; s++) {
      int v = nhist[s * 64 + tid];
      int inc = v;
      #pragma unroll
      for (int d = 1; d < 64; d <<= 1) {
        int tt = __shfl_up(inc, d);
        if (tid >= d) inc += tt;
      }
      ncur[s * 64 + tid] = carry + inc - v;
      carry += __shfl(inc, 63);
    }
  }
  __syncthreads();
  int gk0 = b * KEYS;
  int nk = NNODES * NREL - gk0; if (nk > KEYS) nk = KEYS;
  for (int i = tid; i < nk; i += 1024) roff[gk0 + i] = base + ncur[i];
  if (b == 0 && tid == 0) roff[NNODES * NREL] = NEDGES;
  for (int i = tid; i < KEYS; i += 1024) {
    float d = degf[i];
    degf[i] = (d != 0.f) ? (1.0f / d) : 0.f;
  }
  __syncthreads();
  for (int i = tid; i < cnt; i += 1024) {
    uint2 rec = sb[i];
    int key = (((rec.x >> 19) & 255) << 3) | ((rec.x >> 16) & 7);
    int pos = atomicAdd(&ncur[key], 1);
    float sc = __uint_as_float(rec.y) * degf[key];
    meta[base + pos] = make_uint2(rec.x & 0xFFFF, __float_as_uint(sc));
  }
}

// K3: FUSED aggregate + output GEMM. Block = 16 nodes (4 waves x 4 nodes).
// Phase 1: per node, wave gathers scaled x[src] rows into acc[8] (update row),
// stages [update | x_self] (16 x 576 bf16) into LDS.
// Phase 2: each wave does one 16-col MFMA tile of (16x576)@(576x64), + bias, relu.
__global__ __launch_bounds__(256) void fused_kernel(const int* __restrict__ roff,
                                                    const uint2* __restrict__ meta,
                                                    const unsigned short* __restrict__ xb,
                                                    const unsigned short* __restrict__ Bf2,
                                                    const float* __restrict__ bsum,
                                                    float* __restrict__ out) {
  __shared__ unsigned short At[16 * APITCH];   // 18.25 KB
  int wave = threadIdx.x >> 6;
  int lane = threadIdx.x & 63;
  int nodeBase = blockIdx.x * 16;

  #pragma unroll
  for (int i = 0; i < 4; i++) {
    int row  = wave * 4 + i;
    int node = nodeBase + row;
    int bnd = 0;
    if (lane < 9) bnd = roff[node * NREL + lane];
    int b0  = __shfl(bnd, 0);
    int cnt = __shfl(bnd, 8) - b0;
    int cl  = (cnt < 64) ? cnt : 64;

    uint2 mm = make_uint2(0u, 0u);
    if (lane < cl) mm = meta[b0 + lane];           // coalesced 8B/lane
    int   off_l = (mm.x & 0xFFFF) * 64;
    float sc_l  = __uint_as_float(mm.y);

    float acc[8];
    #pragma unroll
    for (int r = 0; r < 8; r++) acc[r] = 0.f;

    #pragma unroll
    for (int r = 0; r < 8; r++) {
      int e0 = __shfl(bnd, r) - b0;
      int e1 = __shfl(bnd, r + 1) - b0;
      int jend = (e1 < 64) ? e1 : 64;
      int j = (e0 < jend) ? e0 : jend;
      for (; j + 2 <= jend; j += 2) {
        int   o0 = __shfl(off_l, j), o1 = __shfl(off_l, j + 1);
        float s0 = __shfl(sc_l, j),  s1 = __shfl(sc_l, j + 1);
        float v0 = bf2f(xb[o0 + lane]);
        float v1 = bf2f(xb[o1 + lane]);
        acc[r] += s0 * v0;
        acc[r] += s1 * v1;
      }
      for (; j < jend; j++) {
        int   o = __shfl(off_l, j);
        float s = __shfl(sc_l, j);
        acc[r] += s * bf2f(xb[o + lane]);
      }
      // rare tail (node degree > 64)
      int estart = (e0 > 64) ? e0 : 64;
      for (int e = estart; e < e1; e++) {
        uint2 m = meta[b0 + e];
        acc[r] += __uint_as_float(m.y) * bf2f(xb[(m.x & 0xFFFF) * 64 + lane]);
      }
    }
    unsigned short* ar = At + row * APITCH;
    #pragma unroll
    for (int r = 0; r < 8; r++) ar[r * 64 + lane] = f2bf(acc[r]);
    ar[512 + lane] = xb[(size_t)node * 64 + lane];   // self-loop block
  }
  __syncthreads();

  // Phase 2: MFMA. This wave's col tile ct = wave.
  int q = lane >> 4;
  int m = lane & 15;
  float4v acc4 = {0.f, 0.f, 0.f, 0.f};
  const short8* Bp = (const short8*)Bf2;
  #pragma unroll
  for (int ks = 0; ks < 18; ks++) {
    short8 a = *(const short8*)(At + m * APITCH + ks * 32 + q * 8);
    short8 bfr = Bp[(ks * 4 + wave) * 64 + lane];
    acc4 = __builtin_amdgcn_mfma_f32_16x16x32_bf16(a, bfr, acc4, 0, 0, 0);
  }
  int c = wave * 16 + m;
  float bias = bsum[c];
  #pragma unroll
  for (int rr = 0; rr < 4; rr++) {
    out[(size_t)(nodeBase + q * 4 + rr) * 64 + c] = fmaxf(acc4[rr] + bias, 0.0f);
  }
}

extern "C" void kernel_launch(void* const* d_in, const int* in_sizes, int n_in,
                              void* d_out, int out_size, void* d_ws, size_t ws_size,
                              hipStream_t stream) {
  const float* x     = (const float*)d_in[0];
  const int*   esrc  = (const int*)d_in[1];
  const int*   edst  = (const int*)d_in[2];
  const int*   erel  = (const int*)d_in[3];
  const float* ew    = (const float*)d_in[4];
  const float* Wlin  = (const float*)d_in[5];
  const float* blin  = (const float*)d_in[6];
  const float* Wself = (const float*)d_in[7];
  const float* bself = (const float*)d_in[8];
  float* out = (float*)d_out;

  char* ws = (char*)d_ws;
  size_t off = 0;
  auto alloc = [&](size_t bytes) -> void* {
    void* p = ws + off;
    off += (bytes + 255) & ~(size_t)255;
    return p;
  };
  int*            bucket_cursor = (int*)alloc((size_t)NBUCK * sizeof(int));            // zeroed in cast
  int*            roff    = (int*)alloc((size_t)(NNODES * NREL + 8) * sizeof(int));    // 1.6 MB
  uint2*          staged  = (uint2*)alloc((size_t)NBUCK * BCAP * sizeof(uint2));       // 8.8 MB
  uint2*          meta    = (uint2*)alloc((size_t)NEDGES * sizeof(uint2));             // 8 MB
  unsigned short* Bf2     = (unsigned short*)alloc((size_t)18 * 4 * 64 * 8 * sizeof(unsigned short));
  float*          bsum    = (float*)alloc(64 * sizeof(float));
  unsigned short* xb      = (unsigned short*)alloc((size_t)NNODES * DIM * sizeof(unsigned short));   // 6.4 MB

  const int E4 = NEDGES / 4;
  const int X4 = NNODES * DIM / 4;
  prep_kernel<<<(18 * 4 * 64 * 8 + 255) / 256, 256, 0, stream>>>(Wlin, Wself, blin, bself, Bf2, bsum);
  cast_kernel<<<(X4 + 255) / 256, 256, 0, stream>>>((const float4*)x, (us4*)xb, bucket_cursor, X4);
  binscatter_kernel<<<(E4 + 1023) / 1024, 1024, 0, stream>>>((const int4*)esrc, (const int4*)edst,
                                                             (const int4*)erel, (const float4*)ew,
                                                             bucket_cursor, staged, E4);
  csrbuild_kernel<<<NBUCK, 1024, 0, stream>>>(bucket_cursor, staged, meta, roff);
  fused_kernel<<<NNODES / 16, 256, 0, stream>>>(roff, meta, xb, Bf2, bsum, out);
}